// Round 4
// baseline (29747.769 us; speedup 1.0000x reference)
//
#include <hip/hip_runtime.h>

// ============================================================================
// AttnDecoderRNN: persistent-kernel design (round 4)
//   B=64, S=256, H=512, V=512.  256-step scan, 3 grid barriers/step.
//   R4: cut uncached (sc-flagged, L2-bypass) read volume ~4x -- it matched
//   FETCH_SIZE 14 MB/step at ~400 GB/s = the missing 36 us/step:
//    - Phase A: 16 blocks x 10 tiles (hbf convoy 10 MB -> 1 MB/step)
//    - Phase C: 8 blocks x 64 rows/gate (ctx convoy 4 MB -> 1 MB/step)
//    - barrier: per-leaf done flags (32 pollers/line, not 256) + s_sleep(4)
//    - Phase B: Ek=exp(2*keys) precomputed (1 transcendental/elem, not 2)
// ============================================================================

typedef short s8v __attribute__((ext_vector_type(8)));
typedef float f4v __attribute__((ext_vector_type(4)));

// ws layout (bytes)
#define OFF_BAR   0u
#define OFF_H     1024u
#define OFF_HBF   132096u
#define OFF_Q     197632u
#define OFF_GH    328704u
#define OFF_CTX   721920u
#define OFF_ZP    852992u
#define OFF_WEXP  854016u
#define OFF_WCAT  919552u
#define OFF_WIH   3540992u
#define OFF_UAB   5113856u
#define OFF_KEYS  5638144u
#define OFF_ENCB  22415360u
#define WS_FULL   39192576u
#define MEMSET_BYTES 197632u   // barrier + h_f32 + h_bf16

#define OUT_LOGITS 0u
#define OUT_HFIN   8388608u
#define OUT_ATTN   8421376u

__device__ __forceinline__ unsigned short f2bf(float f) {
  union { float f; unsigned u; } a; a.f = f;
  unsigned r = a.u + 0x7fffu + ((a.u >> 16) & 1u);
  return (unsigned short)(r >> 16);
}
__device__ __forceinline__ float bfbits2f(unsigned bits) {
  union { unsigned u; float f; } a; a.u = bits; return a.f;
}
__device__ __forceinline__ float bf2f(unsigned short h) { return bfbits2f((unsigned)h << 16); }

// agent-scope coherent (LLC) load/store -- cross-block state
__device__ __forceinline__ float cload(const float* p) {
  return __hip_atomic_load(p, __ATOMIC_RELAXED, __HIP_MEMORY_SCOPE_AGENT);
}
__device__ __forceinline__ void cstore(float* p, float v) {
  __hip_atomic_store(p, v, __ATOMIC_RELAXED, __HIP_MEMORY_SCOPE_AGENT);
}
__device__ __forceinline__ unsigned long long cload64(const unsigned long long* p) {
  return __hip_atomic_load(p, __ATOMIC_RELAXED, __HIP_MEMORY_SCOPE_AGENT);
}
__device__ __forceinline__ void cstore64(unsigned long long* p, unsigned long long v) {
  __hip_atomic_store(p, v, __ATOMIC_RELAXED, __HIP_MEMORY_SCOPE_AGENT);
}
__device__ __forceinline__ unsigned long long pack2f(float a, float b) {
  union { float f[2]; unsigned long long u; } x; x.f[0] = a; x.f[1] = b; return x.u;
}

__device__ __forceinline__ float sigm(float x) {
  return __builtin_amdgcn_rcpf(1.f + __expf(-x));
}
__device__ __forceinline__ float tanh2(float x) {
  return 1.f - 2.f * __builtin_amdgcn_rcpf(1.f + __expf(x + x));
}
__device__ __forceinline__ f4v mfma16(s8v a, s8v b, f4v c) {
  return __builtin_amdgcn_mfma_f32_16x16x32_bf16(a, b, c, 0, 0, 0);
}

// ---------------------------------------------------------------------------
// two-level grid barrier, relaxed.  8 leaf counters (idx 0,16,..,112), root
// (idx 120), 8 per-leaf done flags (idx 128,144,..,240 -- one 64B line each).
// Root-setter fans out to 8 flags; each leader polls only its leaf's flag
// (32 pollers/line) with s_sleep(4) between polls -> no MALL line congestion.
// ---------------------------------------------------------------------------
__device__ __forceinline__ void gbar(unsigned* bar, unsigned& gen) {
  asm volatile("s_waitcnt vmcnt(0) lgkmcnt(0)" ::: "memory");
  __syncthreads();
  if (threadIdx.x == 0) {
    __atomic_signal_fence(__ATOMIC_SEQ_CST);
    gen++;
    const int leaf = blockIdx.x >> 5;
    unsigned old = __hip_atomic_fetch_add(bar + leaf * 16, 1u, __ATOMIC_RELAXED,
                                          __HIP_MEMORY_SCOPE_AGENT);
    if (old == gen * 32u - 1u) {
      unsigned ro = __hip_atomic_fetch_add(bar + 120, 1u, __ATOMIC_RELAXED,
                                           __HIP_MEMORY_SCOPE_AGENT);
      if (ro == gen * 8u - 1u) {
#pragma unroll
        for (int l = 0; l < 8; ++l)
          __hip_atomic_store(bar + 128 + l * 16, gen, __ATOMIC_RELAXED,
                             __HIP_MEMORY_SCOPE_AGENT);
      }
    }
    while (__hip_atomic_load(bar + 128 + leaf * 16, __ATOMIC_RELAXED,
                             __HIP_MEMORY_SCOPE_AGENT) < gen)
      __builtin_amdgcn_s_sleep(4);
    __atomic_signal_fence(__ATOMIC_SEQ_CST);
  }
  __syncthreads();
}

// ---------------------------------------------------------------------------
// prep: bf16 conversions.  wcat rows: [0,512)=Wa, [512,2048)=W_hh, [2048,2560)=Wout
// ---------------------------------------------------------------------------
__global__ void __launch_bounds__(256) prep_kernel(
    const float* __restrict__ Wa, const float* __restrict__ Whh,
    const float* __restrict__ Wout, const float* __restrict__ Wih,
    const float* __restrict__ Ua, const float* __restrict__ enc,
    unsigned short* __restrict__ wcat, unsigned short* __restrict__ wihb,
    unsigned short* __restrict__ uab, unsigned short* __restrict__ encb,
    int use_encb) {
  size_t n_total = use_encb ? 10747904u : 2359296u;
  for (size_t i = (size_t)blockIdx.x * 256 + threadIdx.x; i < n_total;
       i += (size_t)gridDim.x * 256) {
    float v; unsigned short* d;
    if (i < 1310720u) {
      v = (i < 262144u) ? Wa[i] : (i < 1048576u) ? Whh[i - 262144u] : Wout[i - 1048576u];
      d = wcat + i;
    } else if (i < 2097152u) { v = Wih[i - 1310720u]; d = wihb + (i - 1310720u); }
    else if (i < 2359296u)   { v = Ua[i - 2097152u];  d = uab  + (i - 2097152u); }
    else                     { v = enc[i - 2359296u]; d = encb + (i - 2359296u); }
    *d = f2bf(v);
  }
}

// ---------------------------------------------------------------------------
// Ek = exp(2*(enc @ Ua^T + bu))  (bf16 out).  M=16384,N=512,K=512.
// exp(2x) precomputed so per-step tanh needs only a reciprocal:
//   tanh(q+k) = 1 - 2/(1 + Ek*Eq),  Eq = exp(2q).
// Range: |q+k| <~ 20 -> Ek,Eq <= e^40-ish, products < 1e31 << f32 max.  bf16
// rel err 2^-9 on Ek perturbs scores by ~1e-3 -- negligible vs threshold.
// ---------------------------------------------------------------------------
__global__ void __launch_bounds__(256) keys_kernel(
    const float* __restrict__ enc, const unsigned short* __restrict__ uab,
    const float* __restrict__ bu, unsigned short* __restrict__ keysb) {
  const int tid = threadIdx.x;
  const int w = tid >> 6, lane = tid & 63, ln = lane & 15, kq = lane >> 4;
  const int mb = blockIdx.x >> 3, nb = blockIdx.x & 7;
  const int mrow = mb * 64 + w * 16 + ln;
  f4v acc[4] = {{0,0,0,0},{0,0,0,0},{0,0,0,0},{0,0,0,0}};
  for (int ks = 0; ks < 16; ++ks) {
    const float* ap = enc + (size_t)mrow * 512 + ks * 32 + kq * 8;
    s8v af;
#pragma unroll
    for (int j = 0; j < 8; ++j) af[j] = (short)f2bf(ap[j]);
#pragma unroll
    for (int nt = 0; nt < 4; ++nt) {
      int n = nb * 64 + nt * 16 + ln;
      s8v bf = ((const s8v*)(uab + (size_t)n * 512))[ks * 4 + kq];
      acc[nt] = mfma16(af, bf, acc[nt]);
    }
  }
#pragma unroll
  for (int nt = 0; nt < 4; ++nt) {
    int n = nb * 64 + nt * 16 + ln;
    float bias = bu[n];
#pragma unroll
    for (int r = 0; r < 4; ++r) {
      int gm = mb * 64 + w * 16 + kq * 4 + r;
      keysb[(size_t)gm * 512 + n] = f2bf(__expf(2.f * (acc[nt][r] + bias)));
    }
  }
}

// ---------------------------------------------------------------------------
// persistent decoder
// ---------------------------------------------------------------------------
__global__ void __launch_bounds__(256, 1) decoder_kernel(
    const float* __restrict__ enc, const float* __restrict__ ba_,
    const float* __restrict__ va_, const float* __restrict__ bih_,
    const float* __restrict__ bhh_, const float* __restrict__ bout_,
    const unsigned short* __restrict__ wcat, const unsigned short* __restrict__ wih,
    const unsigned short* __restrict__ keysb, const unsigned short* __restrict__ encb,
    unsigned* __restrict__ bar, float* __restrict__ hst,
    unsigned short* __restrict__ hbf, float* __restrict__ qst,
    float* __restrict__ ghst, float* __restrict__ ctxst,
    float* __restrict__ zpst, float* __restrict__ wexpst,
    float* __restrict__ out, int use_encb) {
  const int bid = blockIdx.x, tid = threadIdx.x;
  const int w = tid >> 6, lane = tid & 63, ln = lane & 15, kq = lane >> 4;
  __shared__ float s_w[64];
  unsigned gen = 0;
  float* logits = out + OUT_LOGITS;
  float* hfin = out + OUT_HFIN;
  float* attn = out + OUT_ATTN;

  // ---- hoisted loop invariants (Phase B) ----
  const int pb_b = bid >> 2, pb_p = bid & 3;
  float vav[8]; float vasum = 0.f;
#pragma unroll
  for (int j = 0; j < 8; ++j) { vav[j] = va_[lane * 8 + j]; vasum += vav[j]; }
#pragma unroll
  for (int off = 32; off > 0; off >>= 1) vasum += __shfl_xor(vasum, off, 64);

#pragma clang loop unroll(disable)
  for (int it = 0; it <= 256; ++it) {
    // ------- Phase A: [q|gh|logits_prev] = h @ Wcat^T + bias (16 blocks) ----
    if (bid < 16) {
      // one convoy: the whole hbf A-fragment set (256 B/lane), reused x10 tiles
      const unsigned long long* hb =
          (const unsigned long long*)(hbf + (size_t)(w * 16 + ln) * 512);
      union { unsigned long long u[32]; s8v v[16]; } au;
#pragma unroll
      for (int ks = 0; ks < 16; ++ks) {
        au.u[2 * ks]     = cload64(hb + ks * 8 + kq * 2);
        au.u[2 * ks + 1] = cload64(hb + ks * 8 + kq * 2 + 1);
      }
#pragma unroll
      for (int u = 0; u < 10; ++u) {
        const int T = bid * 10 + u;
        const int C0 = T * 16;
        const int rg = (C0 < 512) ? 0 : (C0 < 2048) ? 1 : 2;
        if ((rg == 2 && it == 0) || (rg != 2 && it == 256)) continue;
        const s8v* wp = (const s8v*)(wcat + (size_t)(C0 + ln) * 512);
        f4v acc = {0.f, 0.f, 0.f, 0.f};
#pragma unroll
        for (int ks = 0; ks < 16; ++ks) acc = mfma16(au.v[ks], wp[ks * 4 + kq], acc);
        const int col = C0 + ln;
        float bias = (rg == 0) ? ba_[col] : (rg == 1) ? bhh_[col - 512] : bout_[col - 2048];
#pragma unroll
        for (int r = 0; r < 4; ++r) {
          int b = w * 16 + kq * 4 + r;
          float v = acc[r] + bias;
          if (rg == 0)      cstore(qst + (size_t)b * 512 + col, v);
          else if (rg == 1) cstore(ghst + (size_t)b * 1536 + (col - 512), v);
          else
            cstore(logits + (size_t)(it - 1) * 32768 + (size_t)b * 512 + (col - 2048), v);
        }
      }
    } else if (bid >= 160 && bid < 224 && it < 256) {   // zero ctx accumulator
      int i = (bid - 160) * 512 + tid;
      cstore(ctxst + i, 0.f);
      cstore(ctxst + i + 256, 0.f);
    }
    gbar(bar, gen);
    if (it == 256) break;

    // ------- Phase B: attention (4 blocks per b, 64 s each) -----------------
    {
      const unsigned long long* q64 =
          (const unsigned long long*)(qst + (size_t)pb_b * 512 + lane * 8);
      unsigned long long tq[4];
#pragma unroll
      for (int j = 0; j < 4; ++j) tq[j] = cload64(q64 + j);
      union { unsigned long long u[4]; float f[8]; } qu;
#pragma unroll
      for (int j = 0; j < 4; ++j) qu.u[j] = tq[j];
      float Eq[8];
#pragma unroll
      for (int j = 0; j < 8; ++j) Eq[j] = __expf(2.f * qu.f[j]);
#pragma unroll 4
      for (int i = 0; i < 16; ++i) {
        const int sl = w * 16 + i;
        const s8v kv =
            ((const s8v*)(keysb + (size_t)(pb_b * 256 + pb_p * 64 + sl) * 512))[lane];
        float a2 = 0.f;
#pragma unroll
        for (int j = 0; j < 8; ++j) {
          float P = Eq[j] * bf2f((unsigned short)kv[j]);
          a2 += vav[j] * __builtin_amdgcn_rcpf(1.f + P);
        }
#pragma unroll
        for (int off = 32; off > 0; off >>= 1) a2 += __shfl_xor(a2, off, 64);
        if (lane == 0) s_w[sl] = __expf(vasum - 2.f * a2);  // unnormalized
      }
      __syncthreads();
      float c0 = 0.f, c1 = 0.f;
      if (use_encb) {
#pragma unroll 8
        for (int s = 0; s < 64; ++s) {
          float wt = s_w[s];
          unsigned e = *(const unsigned*)(encb +
              (size_t)(pb_b * 256 + pb_p * 64 + s) * 512 + tid * 2);
          c0 += wt * bfbits2f(e << 16);
          c1 += wt * bfbits2f(e & 0xffff0000u);
        }
      } else {
#pragma unroll 8
        for (int s = 0; s < 64; ++s) {
          float wt = s_w[s];
          float2 e = ((const float2*)(enc + (size_t)(pb_b * 256 + pb_p * 64 + s) * 512))[tid];
          c0 += wt * e.x; c1 += wt * e.y;
        }
      }
      atomicAdd(ctxst + (size_t)pb_b * 512 + tid * 2, c0);
      atomicAdd(ctxst + (size_t)pb_b * 512 + tid * 2 + 1, c1);
      if (tid < 64) {
        float z = s_w[tid];
        cstore(wexpst + (size_t)pb_b * 256 + pb_p * 64 + tid, z);
#pragma unroll
        for (int off = 32; off > 0; off >>= 1) z += __shfl_xor(z, off, 64);
        if (tid == 0) cstore(zpst + pb_b * 4 + pb_p, z);
      }
    }
    gbar(bar, gen);

    // ------- Phase C: gi = W_ih.(ctx/Z) + GRU (8 blocks x 64 rows/gate) -----
    if (bid < 8) {
      const int b = w * 16 + ln;                // MFMA B-operand column = b
      const unsigned long long* zp64 = (const unsigned long long*)(zpst + b * 4);
      const unsigned long long* cx = (const unsigned long long*)(ctxst + (size_t)b * 512);
      unsigned long long tz0 = cload64(zp64), tz1 = cload64(zp64 + 1);
      unsigned long long t[32];
#pragma unroll
      for (int ks = 0; ks < 8; ++ks)
#pragma unroll
        for (int u = 0; u < 4; ++u)
          t[ks * 4 + u] = cload64(cx + ks * 16 + kq * 4 + u);
      union { unsigned long long u; float f[2]; } z0, z1;
      z0.u = tz0; z1.u = tz1;
      float invZ = __builtin_amdgcn_rcpf(z0.f[0] + z0.f[1] + z1.f[0] + z1.f[1]);
      unsigned long long t2[32];
#pragma unroll
      for (int ks = 0; ks < 8; ++ks)
#pragma unroll
        for (int u = 0; u < 4; ++u)
          t2[ks * 4 + u] = cload64(cx + (ks + 8) * 16 + kq * 4 + u);
      s8v bf[16];
#pragma unroll
      for (int ks = 0; ks < 8; ++ks) {
        union { unsigned long long u[4]; float f[8]; } cu;
#pragma unroll
        for (int u = 0; u < 4; ++u) cu.u[u] = t[ks * 4 + u];
#pragma unroll
        for (int j = 0; j < 8; ++j) bf[ks][j] = (short)f2bf(cu.f[j] * invZ);
      }
      // GRU-state convoy (overlaps the t2 wait and the MFMAs)
      const unsigned long long* gh64 = (const unsigned long long*)(ghst + (size_t)b * 1536);
      const unsigned long long* h64  = (const unsigned long long*)(hst + (size_t)b * 512);
      unsigned long long tg[24], th[8];
#pragma unroll
      for (int g = 0; g < 3; ++g)
#pragma unroll
        for (int u = 0; u < 4; ++u) {
          int cq = (g * 512 + bid * 64 + u * 16 + kq * 4) >> 1;
          tg[(g * 4 + u) * 2]     = cload64(gh64 + cq);
          tg[(g * 4 + u) * 2 + 1] = cload64(gh64 + cq + 1);
        }
#pragma unroll
      for (int u = 0; u < 4; ++u) {
        int cq = (bid * 64 + u * 16 + kq * 4) >> 1;
        th[u * 2] = cload64(h64 + cq); th[u * 2 + 1] = cload64(h64 + cq + 1);
      }
#pragma unroll
      for (int ks = 0; ks < 8; ++ks) {
        union { unsigned long long u[4]; float f[8]; } cu;
#pragma unroll
        for (int u = 0; u < 4; ++u) cu.u[u] = t2[ks * 4 + u];
#pragma unroll
        for (int j = 0; j < 8; ++j) bf[8 + ks][j] = (short)f2bf(cu.f[j] * invZ);
      }
      f4v acc[3][4];
#pragma unroll
      for (int g = 0; g < 3; ++g)
#pragma unroll
        for (int u = 0; u < 4; ++u) acc[g][u] = (f4v){0.f, 0.f, 0.f, 0.f};
#pragma unroll
      for (int g = 0; g < 3; ++g)
#pragma unroll
        for (int u = 0; u < 4; ++u) {
          const s8v* wp =
              (const s8v*)(wih + (size_t)(g * 512 + bid * 64 + u * 16 + ln) * 512);
#pragma unroll
          for (int ks = 0; ks < 16; ++ks)
            acc[g][u] = mfma16(wp[ks * 4 + kq], bf[ks], acc[g][u]);
        }
#pragma unroll
      for (int u = 0; u < 4; ++u) {
        int c0 = bid * 64 + u * 16 + kq * 4;
        union { unsigned long long u2[2]; float f[4]; } gr, gz, gn, hh;
        gr.u2[0] = tg[(0 + u) * 2];      gr.u2[1] = tg[(0 + u) * 2 + 1];
        gz.u2[0] = tg[(4 + u) * 2];      gz.u2[1] = tg[(4 + u) * 2 + 1];
        gn.u2[0] = tg[(8 + u) * 2];      gn.u2[1] = tg[(8 + u) * 2 + 1];
        hh.u2[0] = th[u * 2];            hh.u2[1] = th[u * 2 + 1];
        float hn[4]; unsigned short h4[4];
#pragma unroll
        for (int r = 0; r < 4; ++r) {
          int c = c0 + r;
          float rg2 = sigm(acc[0][u][r] + bih_[c] + gr.f[r]);
          float zg  = sigm(acc[1][u][r] + bih_[512 + c] + gz.f[r]);
          float ng  = tanh2(acc[2][u][r] + bih_[1024 + c] + rg2 * gn.f[r]);
          hn[r] = (1.f - zg) * ng + zg * hh.f[r];
          h4[r] = f2bf(hn[r]);
        }
        cstore64((unsigned long long*)(hst + (size_t)b * 512 + c0), pack2f(hn[0], hn[1]));
        cstore64((unsigned long long*)(hst + (size_t)b * 512 + c0 + 2), pack2f(hn[2], hn[3]));
        union { unsigned short s[4]; unsigned long long u2; } hb4;
        hb4.s[0] = h4[0]; hb4.s[1] = h4[1]; hb4.s[2] = h4[2]; hb4.s[3] = h4[3];
        cstore64((unsigned long long*)(hbf + (size_t)b * 512 + c0), hb4.u2);
      }
    } else if (bid >= 64 && bid < 128) {          // attention output, 1 block/b
      const int b = bid - 64;
      unsigned long long tz0 = cload64((const unsigned long long*)(zpst + b * 4));
      unsigned long long tz1 = cload64((const unsigned long long*)(zpst + b * 4) + 1);
      float we = cload(wexpst + (size_t)b * 256 + tid);
      union { unsigned long long u; float f[2]; } z0, z1;
      z0.u = tz0; z1.u = tz1;
      float Z = z0.f[0] + z0.f[1] + z1.f[0] + z1.f[1];
      attn[(size_t)b * 65536 + (size_t)it * 256 + tid] = we * __builtin_amdgcn_rcpf(Z);
    }
    gbar(bar, gen);
  }

  // -------- final: log_softmax, wave-per-row (plain cached loads are safe:
  // logits lines were only ever sc1-written during the kernel, never cached) --
  for (int rit = 0; rit < 16; ++rit) {
    int row = bid * 64 + rit * 4 + w;
    float* xr = logits + (size_t)row * 512;
    f4v a = ((const f4v*)xr)[lane * 2];
    f4v b2 = ((const f4v*)xr)[lane * 2 + 1];
    float m = a[0];
#pragma unroll
    for (int j = 1; j < 4; ++j) m = fmaxf(m, a[j]);
#pragma unroll
    for (int j = 0; j < 4; ++j) m = fmaxf(m, b2[j]);
#pragma unroll
    for (int off = 32; off > 0; off >>= 1) m = fmaxf(m, __shfl_xor(m, off, 64));
    float sm = 0.f;
#pragma unroll
    for (int j = 0; j < 4; ++j) sm += __expf(a[j] - m) + __expf(b2[j] - m);
#pragma unroll
    for (int off = 32; off > 0; off >>= 1) sm += __shfl_xor(sm, off, 64);
    float lse = m + __logf(sm);
    f4v oa, ob;
#pragma unroll
    for (int j = 0; j < 4; ++j) { oa[j] = a[j] - lse; ob[j] = b2[j] - lse; }
    ((f4v*)xr)[lane * 2] = oa;
    ((f4v*)xr)[lane * 2 + 1] = ob;
  }
  {
    int i = bid * 256 + tid;                    // h_final (blocks 0..127)
    if (i < 32768) hfin[i] = cload(hst + i);
  }
}

// ---------------------------------------------------------------------------
extern "C" void kernel_launch(void* const* d_in, const int* in_sizes, int n_in,
                              void* d_out, int out_size, void* d_ws, size_t ws_size,
                              hipStream_t stream) {
  const float* enc  = (const float*)d_in[0];
  const float* Wa   = (const float*)d_in[1];
  const float* ba   = (const float*)d_in[2];
  const float* Ua   = (const float*)d_in[3];
  const float* bu   = (const float*)d_in[4];
  const float* Va   = (const float*)d_in[5];
  // d_in[6] = bv : constant shift, softmax-invariant -> unused
  const float* Wih  = (const float*)d_in[7];
  const float* bih  = (const float*)d_in[8];
  const float* Whh  = (const float*)d_in[9];
  const float* bhh  = (const float*)d_in[10];
  const float* Wout = (const float*)d_in[11];
  const float* bout = (const float*)d_in[12];
  (void)in_sizes; (void)n_in; (void)out_size;

  char* ws = (char*)d_ws;
  unsigned*       bar   = (unsigned*)(ws + OFF_BAR);
  float*          hst   = (float*)(ws + OFF_H);
  unsigned short* hbf   = (unsigned short*)(ws + OFF_HBF);
  float*          qst   = (float*)(ws + OFF_Q);
  float*          ghst  = (float*)(ws + OFF_GH);
  float*          ctxst = (float*)(ws + OFF_CTX);
  float*          zpst  = (float*)(ws + OFF_ZP);
  float*          wexp  = (float*)(ws + OFF_WEXP);
  unsigned short* wcat  = (unsigned short*)(ws + OFF_WCAT);
  unsigned short* wihb  = (unsigned short*)(ws + OFF_WIH);
  unsigned short* uab   = (unsigned short*)(ws + OFF_UAB);
  unsigned short* keysb = (unsigned short*)(ws + OFF_KEYS);
  unsigned short* encb  = (unsigned short*)(ws + OFF_ENCB);
  int use_encb = (ws_size >= (size_t)WS_FULL) ? 1 : 0;

  hipMemsetAsync(d_ws, 0, MEMSET_BYTES, stream);  // barrier + h + h_bf16 = 0
  prep_kernel<<<1024, 256, 0, stream>>>(Wa, Whh, Wout, Wih, Ua, enc,
                                        wcat, wihb, uab, encb, use_encb);
  keys_kernel<<<2048, 256, 0, stream>>>(enc, uab, bu, keysb);
  decoder_kernel<<<256, 256, 0, stream>>>(enc, ba, Va, bih, bhh, bout,
                                          wcat, wihb, keysb, encb,
                                          bar, hst, hbf, qst, ghst, ctxst,
                                          zpst, wexp, (float*)d_out, use_encb);
}

// Round 5
// 10124.866 us; speedup vs baseline: 2.9381x; 2.9381x over previous
//
#include <hip/hip_runtime.h>

// ============================================================================
// AttnDecoderRNN: persistent-kernel design (round 5)
//   B=64, S=256, H=512, V=512.  256-step scan, 3 grid barriers/step.
//   R5 = R3 skeleton (VGPR~120, no spills) + L2-thrash fixes:
//    - FETCH 14 MB/step == keysb+encb re-read/step; per-XCD set was 4 MB = L2.
//    - Phase B XCD swizzle: bid%8=XCD, each XCD serves 8 contiguous b's.
//    - enc stored fp8 e4m3 (weighted-avg input, error-tolerant): 16->8 MB.
//      Per-XCD: keys 2.1 MB + enc8 1.05 MB + weights ~0.5 MB < 4 MiB L2.
//    - keys kernel stores Ek=exp(2*keys): score tanh = 1-2/(1+Ek*Eq), one
//      rcp per element instead of exp+rcp.
//    - barrier: root/leaf/flag on separate 64B lines, per-leaf fanout flags
//      (32 pollers/line), s_sleep(1).
//   R4 lesson: NO giant per-thread arrays (spill/fill on the critical path).
// ============================================================================

typedef short s8v __attribute__((ext_vector_type(8)));
typedef float f4v __attribute__((ext_vector_type(4)));
typedef float f2v __attribute__((ext_vector_type(2)));

// ws layout (bytes)
#define OFF_BAR   0u
#define OFF_H     2048u
#define OFF_HBF   133120u
#define OFF_Q     198656u
#define OFF_GH    329728u
#define OFF_CTX   722944u
#define OFF_ZP    854016u
#define OFF_WEXP  855040u
#define OFF_WCAT  920576u
#define OFF_WIH   3542016u
#define OFF_UAB   5114880u
#define OFF_KEYS  5639168u
#define OFF_ENC8  22416384u
#define WS_FULL   30804992u
#define MEMSET_BYTES 198656u   // barrier + h_f32 + h_bf16

#define OUT_LOGITS 0u
#define OUT_HFIN   8388608u
#define OUT_ATTN   8421376u

__device__ __forceinline__ unsigned short f2bf(float f) {
  union { float f; unsigned u; } a; a.f = f;
  unsigned r = a.u + 0x7fffu + ((a.u >> 16) & 1u);
  return (unsigned short)(r >> 16);
}
__device__ __forceinline__ float bfbits2f(unsigned bits) {
  union { unsigned u; float f; } a; a.u = bits; return a.f;
}
__device__ __forceinline__ float bf2f(unsigned short h) { return bfbits2f((unsigned)h << 16); }

// agent-scope coherent (LLC) load/store -- cross-block state
__device__ __forceinline__ float cload(const float* p) {
  return __hip_atomic_load(p, __ATOMIC_RELAXED, __HIP_MEMORY_SCOPE_AGENT);
}
__device__ __forceinline__ void cstore(float* p, float v) {
  __hip_atomic_store(p, v, __ATOMIC_RELAXED, __HIP_MEMORY_SCOPE_AGENT);
}
__device__ __forceinline__ unsigned long long cload64(const unsigned long long* p) {
  return __hip_atomic_load(p, __ATOMIC_RELAXED, __HIP_MEMORY_SCOPE_AGENT);
}
__device__ __forceinline__ void cstore64(unsigned long long* p, unsigned long long v) {
  __hip_atomic_store(p, v, __ATOMIC_RELAXED, __HIP_MEMORY_SCOPE_AGENT);
}
__device__ __forceinline__ unsigned long long pack2f(float a, float b) {
  union { float f[2]; unsigned long long u; } x; x.f[0] = a; x.f[1] = b; return x.u;
}

__device__ __forceinline__ float sigm(float x) {
  return __builtin_amdgcn_rcpf(1.f + __expf(-x));
}
__device__ __forceinline__ float tanh2(float x) {
  return 1.f - 2.f * __builtin_amdgcn_rcpf(1.f + __expf(x + x));
}
__device__ __forceinline__ f4v mfma16(s8v a, s8v b, f4v c) {
  return __builtin_amdgcn_mfma_f32_16x16x32_bf16(a, b, c, 0, 0, 0);
}

// ---------------------------------------------------------------------------
// two-level grid barrier, fully relaxed.  Layout (unsigned idx into bar):
//   [0]           root counter          (line 0)
//   [16+16*l]     leaf counters l=0..7  (lines 1..8)
//   [160+16*l]    per-leaf done flags   (lines 10..17)
// Root-setter fans out to the 8 flags; each leader polls only its leaf's
// flag (32 pollers/line) with s_sleep(1).  No release (no wbl2 L2 walk);
// vmcnt drained before arrive; cross-block data is sc-flagged to the LLC.
// ---------------------------------------------------------------------------
__device__ __forceinline__ void gbar(unsigned* bar, unsigned& gen) {
  asm volatile("s_waitcnt vmcnt(0) lgkmcnt(0)" ::: "memory");
  __syncthreads();
  if (threadIdx.x == 0) {
    __atomic_signal_fence(__ATOMIC_SEQ_CST);
    gen++;
    const int leaf = blockIdx.x >> 5;
    unsigned old = __hip_atomic_fetch_add(bar + 16 + leaf * 16, 1u, __ATOMIC_RELAXED,
                                          __HIP_MEMORY_SCOPE_AGENT);
    if (old == gen * 32u - 1u) {
      unsigned ro = __hip_atomic_fetch_add(bar, 1u, __ATOMIC_RELAXED,
                                           __HIP_MEMORY_SCOPE_AGENT);
      if (ro == gen * 8u - 1u) {
#pragma unroll
        for (int l = 0; l < 8; ++l)
          __hip_atomic_store(bar + 160 + l * 16, gen, __ATOMIC_RELAXED,
                             __HIP_MEMORY_SCOPE_AGENT);
      }
    }
    while (__hip_atomic_load(bar + 160 + leaf * 16, __ATOMIC_RELAXED,
                             __HIP_MEMORY_SCOPE_AGENT) < gen)
      __builtin_amdgcn_s_sleep(1);
    __atomic_signal_fence(__ATOMIC_SEQ_CST);
  }
  __syncthreads();
}

// ---------------------------------------------------------------------------
// prep: weights -> bf16; enc -> fp8 e4m3 pairs (v_cvt_pk_fp8_f32).
// wcat rows: [0,512)=Wa, [512,2048)=W_hh, [2048,2560)=Wout
// ---------------------------------------------------------------------------
__global__ void __launch_bounds__(256) prep_kernel(
    const float* __restrict__ Wa, const float* __restrict__ Whh,
    const float* __restrict__ Wout, const float* __restrict__ Wih,
    const float* __restrict__ Ua, const float* __restrict__ enc,
    unsigned short* __restrict__ wcat, unsigned short* __restrict__ wihb,
    unsigned short* __restrict__ uab, unsigned char* __restrict__ enc8,
    int use_enc8) {
  const size_t gid = (size_t)blockIdx.x * 256 + threadIdx.x;
  const size_t stride = (size_t)gridDim.x * 256;
  for (size_t i = gid; i < 2359296u; i += stride) {
    float v; unsigned short* d;
    if (i < 1310720u) {
      v = (i < 262144u) ? Wa[i] : (i < 1048576u) ? Whh[i - 262144u] : Wout[i - 1048576u];
      d = wcat + i;
    } else if (i < 2097152u) { v = Wih[i - 1310720u]; d = wihb + (i - 1310720u); }
    else                     { v = Ua[i - 2097152u];  d = uab  + (i - 2097152u); }
    *d = f2bf(v);
  }
  if (use_enc8) {
    for (size_t j = gid; j < 4194304u; j += stride) {   // 8.4M elems / 2
      float2 e = ((const float2*)enc)[j];
      int pk = __builtin_amdgcn_cvt_pk_fp8_f32(e.x, e.y, 0, false);
      ((unsigned short*)enc8)[j] = (unsigned short)(pk & 0xffff);
    }
  }
}

// ---------------------------------------------------------------------------
// Ek = exp(2*(enc @ Ua^T + bu))  (bf16 out).  M=16384,N=512,K=512.
// Per-step score: tanh(q+k) = 1 - 2/(1+Ek*Eq),  Eq=exp(2q)  -> 1 rcp/elem.
// |q+k| <~ 20 -> products < 1e18, safely inside f32.
// ---------------------------------------------------------------------------
__global__ void __launch_bounds__(256) keys_kernel(
    const float* __restrict__ enc, const unsigned short* __restrict__ uab,
    const float* __restrict__ bu, unsigned short* __restrict__ keysb) {
  const int tid = threadIdx.x;
  const int w = tid >> 6, lane = tid & 63, ln = lane & 15, kq = lane >> 4;
  const int mb = blockIdx.x >> 3, nb = blockIdx.x & 7;
  const int mrow = mb * 64 + w * 16 + ln;
  f4v acc[4] = {{0,0,0,0},{0,0,0,0},{0,0,0,0},{0,0,0,0}};
  for (int ks = 0; ks < 16; ++ks) {
    const float* ap = enc + (size_t)mrow * 512 + ks * 32 + kq * 8;
    s8v af;
#pragma unroll
    for (int j = 0; j < 8; ++j) af[j] = (short)f2bf(ap[j]);
#pragma unroll
    for (int nt = 0; nt < 4; ++nt) {
      int n = nb * 64 + nt * 16 + ln;
      s8v bf = ((const s8v*)(uab + (size_t)n * 512))[ks * 4 + kq];
      acc[nt] = mfma16(af, bf, acc[nt]);
    }
  }
#pragma unroll
  for (int nt = 0; nt < 4; ++nt) {
    int n = nb * 64 + nt * 16 + ln;
    float bias = bu[n];
#pragma unroll
    for (int r = 0; r < 4; ++r) {
      int gm = mb * 64 + w * 16 + kq * 4 + r;
      keysb[(size_t)gm * 512 + n] = f2bf(__expf(2.f * (acc[nt][r] + bias)));
    }
  }
}

// ---------------------------------------------------------------------------
// persistent decoder
// ---------------------------------------------------------------------------
__global__ void __launch_bounds__(256, 1) decoder_kernel(
    const float* __restrict__ enc, const float* __restrict__ ba_,
    const float* __restrict__ va_, const float* __restrict__ bih_,
    const float* __restrict__ bhh_, const float* __restrict__ bout_,
    const unsigned short* __restrict__ wcat, const unsigned short* __restrict__ wih,
    const unsigned short* __restrict__ keysb, const unsigned char* __restrict__ enc8,
    unsigned* __restrict__ bar, float* __restrict__ hst,
    unsigned short* __restrict__ hbf, float* __restrict__ qst,
    float* __restrict__ ghst, float* __restrict__ ctxst,
    float* __restrict__ zpst, float* __restrict__ wexpst,
    float* __restrict__ out, int use_enc8) {
  const int bid = blockIdx.x, tid = threadIdx.x;
  const int w = tid >> 6, lane = tid & 63, ln = lane & 15, kq = lane >> 4;
  __shared__ float s_w[64];
  unsigned gen = 0;
  float* logits = out + OUT_LOGITS;
  float* hfin = out + OUT_HFIN;
  float* attn = out + OUT_ATTN;

  // ---- Phase B invariants: XCD-swizzled (b,p); bid%8 = XCD (empirical) ----
  const int pb_b = (bid & 7) * 8 + ((bid >> 3) >> 2);
  const int pb_p = (bid >> 3) & 3;
  float vav[8]; float vasum = 0.f;
#pragma unroll
  for (int j = 0; j < 8; ++j) { vav[j] = va_[lane * 8 + j]; vasum += vav[j]; }
#pragma unroll
  for (int off = 32; off > 0; off >>= 1) vasum += __shfl_xor(vasum, off, 64);

#pragma clang loop unroll(disable)
  for (int it = 0; it <= 256; ++it) {
    // ---------------- Phase A: [q|gh|logits_prev] = h @ Wcat^T + bias -------
    if (bid < 160) {
      const int C0 = bid * 16;
      const int rg = (C0 < 512) ? 0 : (C0 < 2048) ? 1 : 2;
      if (!((rg == 2 && it == 0) || (rg != 2 && it == 256))) {
        const s8v* wp = (const s8v*)(wcat + (size_t)(C0 + ln) * 512);
        const unsigned long long* hb =
            (const unsigned long long*)(hbf + (size_t)(w * 16 + ln) * 512);
        // batched LLC loads: issue all 32, consume after (1 round trip)
        unsigned long long t[32];
#pragma unroll
        for (int ks = 0; ks < 16; ++ks) {
          t[2 * ks]     = cload64(hb + ks * 8 + kq * 2);
          t[2 * ks + 1] = cload64(hb + ks * 8 + kq * 2 + 1);
        }
        f4v acc = {0.f, 0.f, 0.f, 0.f};
#pragma unroll
        for (int ks = 0; ks < 16; ++ks) {
          union { unsigned long long u[2]; s8v v; } au;
          au.u[0] = t[2 * ks]; au.u[1] = t[2 * ks + 1];
          acc = mfma16(au.v, wp[ks * 4 + kq], acc);
        }
        const int col = C0 + ln;
        float bias = (rg == 0) ? ba_[col] : (rg == 1) ? bhh_[col - 512] : bout_[col - 2048];
#pragma unroll
        for (int r = 0; r < 4; ++r) {
          int b = w * 16 + kq * 4 + r;
          float v = acc[r] + bias;
          if (rg == 0)      cstore(qst + (size_t)b * 512 + col, v);
          else if (rg == 1) cstore(ghst + (size_t)b * 1536 + (col - 512), v);
          else if (it > 0)
            cstore(logits + (size_t)(it - 1) * 32768 + (size_t)b * 512 + (col - 2048), v);
        }
      }
    } else if (bid < 224 && it < 256) {       // zero ctx accumulator
      int i = (bid - 160) * 512 + tid;
      cstore(ctxst + i, 0.f);
      cstore(ctxst + i + 256, 0.f);
    }
    gbar(bar, gen);
    if (it == 256) break;

    // ---------------- Phase B: attention (4 blocks per b, 64 s each) --------
    {
      const unsigned long long* q64 =
          (const unsigned long long*)(qst + (size_t)pb_b * 512 + lane * 8);
      unsigned long long tq[4];
#pragma unroll
      for (int j = 0; j < 4; ++j) tq[j] = cload64(q64 + j);
      union { unsigned long long u[4]; float f[8]; } qu;
#pragma unroll
      for (int j = 0; j < 4; ++j) qu.u[j] = tq[j];
      float Eq[8];
#pragma unroll
      for (int j = 0; j < 8; ++j) Eq[j] = __expf(2.f * qu.f[j]);
#pragma unroll 4
      for (int i = 0; i < 16; ++i) {
        const int sl = w * 16 + i;
        const s8v kv =
            ((const s8v*)(keysb + (size_t)(pb_b * 256 + pb_p * 64 + sl) * 512))[lane];
        float a2 = 0.f;
#pragma unroll
        for (int j = 0; j < 8; ++j) {
          float P = Eq[j] * bf2f((unsigned short)kv[j]);
          a2 += vav[j] * __builtin_amdgcn_rcpf(1.f + P);
        }
#pragma unroll
        for (int off = 32; off > 0; off >>= 1) a2 += __shfl_xor(a2, off, 64);
        if (lane == 0) s_w[sl] = __expf(vasum - 2.f * a2);  // unnormalized
      }
      __syncthreads();
      float c0 = 0.f, c1 = 0.f;                 // ctx partial, 2 h per thread
      if (use_enc8) {
        const unsigned char* ep = enc8 + (size_t)(pb_b * 256 + pb_p * 64) * 512 + tid * 2;
#pragma unroll 8
        for (int s = 0; s < 64; ++s) {
          float wt = s_w[s];
          unsigned short e8 = *(const unsigned short*)(ep + (size_t)s * 512);
          f2v ef = __builtin_amdgcn_cvt_pk_f32_fp8((int)e8, false);
          c0 += wt * ef[0];
          c1 += wt * ef[1];
        }
      } else {
#pragma unroll 8
        for (int s = 0; s < 64; ++s) {
          float wt = s_w[s];
          float2 e = ((const float2*)(enc + (size_t)(pb_b * 256 + pb_p * 64 + s) * 512))[tid];
          c0 += wt * e.x; c1 += wt * e.y;
        }
      }
      atomicAdd(ctxst + (size_t)pb_b * 512 + tid * 2, c0);
      atomicAdd(ctxst + (size_t)pb_b * 512 + tid * 2 + 1, c1);
      if (tid < 64) {
        float z = s_w[tid];
        cstore(wexpst + (size_t)pb_b * 256 + pb_p * 64 + tid, z);
#pragma unroll
        for (int off = 32; off > 0; off >>= 1) z += __shfl_xor(z, off, 64);
        if (tid == 0) cstore(zpst + pb_b * 4 + pb_p, z);
      }
    }
    gbar(bar, gen);

    // ---------------- Phase C: gi = W_ih.(ctx/Z) (transposed) + GRU ---------
    if (bid < 32) {
      const int b = w * 16 + ln;                // D col = b
      const unsigned long long* zp64 = (const unsigned long long*)(zpst + b * 4);
      const unsigned long long* cx = (const unsigned long long*)(ctxst + (size_t)b * 512);
      // batch: Z (2 loads) + ctx first half (32 loads)
      unsigned long long tz0 = cload64(zp64), tz1 = cload64(zp64 + 1);
      unsigned long long t[32];
#pragma unroll
      for (int ks = 0; ks < 8; ++ks)
#pragma unroll
        for (int u = 0; u < 4; ++u)
          t[ks * 4 + u] = cload64(cx + ks * 16 + kq * 4 + u);
      union { unsigned long long u; float f[2]; } z0, z1;
      z0.u = tz0; z1.u = tz1;
      float Z = z0.f[0] + z0.f[1] + z1.f[0] + z1.f[1];
      float invZ = __builtin_amdgcn_rcpf(Z);
      // issue ctx second half while consuming first
      unsigned long long t2[32];
#pragma unroll
      for (int ks = 0; ks < 8; ++ks)
#pragma unroll
        for (int u = 0; u < 4; ++u)
          t2[ks * 4 + u] = cload64(cx + (ks + 8) * 16 + kq * 4 + u);
      f4v ar = {0,0,0,0}, az = {0,0,0,0}, an = {0,0,0,0};
      const s8v* wr = (const s8v*)(wih + (size_t)(bid * 16 + ln) * 512);
      const s8v* wz = (const s8v*)(wih + (size_t)(512 + bid * 16 + ln) * 512);
      const s8v* wn = (const s8v*)(wih + (size_t)(1024 + bid * 16 + ln) * 512);
#pragma unroll
      for (int ks = 0; ks < 16; ++ks) {
        union { unsigned long long u[4]; float f[8]; } cu;
#pragma unroll
        for (int u = 0; u < 4; ++u)
          cu.u[u] = (ks < 8) ? t[ks * 4 + u] : t2[(ks - 8) * 4 + u];
        s8v bfv;
#pragma unroll
        for (int j = 0; j < 8; ++j) bfv[j] = (short)f2bf(cu.f[j] * invZ);
        int idx = ks * 4 + kq;
        ar = mfma16(wr[idx], bfv, ar);
        az = mfma16(wz[idx], bfv, az);
        an = mfma16(wn[idx], bfv, an);
      }
      const int c0i = bid * 16 + kq * 4;        // 4 contiguous hidden units
      const int cq = c0i >> 1;                  // u64 index
      const unsigned long long* gh64 = (const unsigned long long*)(ghst + (size_t)b * 1536);
      const unsigned long long* h64  = (const unsigned long long*)(hst + (size_t)b * 512);
      // batched GRU-state loads (1 round trip)
      unsigned long long tg[8];
      tg[0] = cload64(gh64 + cq);       tg[1] = cload64(gh64 + cq + 1);
      tg[2] = cload64(gh64 + 256 + cq); tg[3] = cload64(gh64 + 256 + cq + 1);
      tg[4] = cload64(gh64 + 512 + cq); tg[5] = cload64(gh64 + 512 + cq + 1);
      tg[6] = cload64(h64 + cq);        tg[7] = cload64(h64 + cq + 1);
      union { unsigned long long u[2]; float f[4]; } gr, gz, gn, hh;
      gr.u[0] = tg[0]; gr.u[1] = tg[1];
      gz.u[0] = tg[2]; gz.u[1] = tg[3];
      gn.u[0] = tg[4]; gn.u[1] = tg[5];
      hh.u[0] = tg[6]; hh.u[1] = tg[7];
      float hn[4]; unsigned short h4[4];
#pragma unroll
      for (int r = 0; r < 4; ++r) {
        int c = c0i + r;
        float rg2 = sigm(ar[r] + bih_[c] + gr.f[r]);
        float zg = sigm(az[r] + bih_[512 + c] + gz.f[r]);
        float ng = tanh2(an[r] + bih_[1024 + c] + rg2 * gn.f[r]);
        hn[r] = (1.f - zg) * ng + zg * hh.f[r];
        h4[r] = f2bf(hn[r]);
      }
      cstore64((unsigned long long*)(hst + (size_t)b * 512 + c0i), pack2f(hn[0], hn[1]));
      cstore64((unsigned long long*)(hst + (size_t)b * 512 + c0i + 2), pack2f(hn[2], hn[3]));
      union { unsigned short s[4]; unsigned long long u; } hb4;
      hb4.s[0] = h4[0]; hb4.s[1] = h4[1]; hb4.s[2] = h4[2]; hb4.s[3] = h4[3];
      cstore64((unsigned long long*)(hbf + (size_t)b * 512 + c0i), hb4.u);
    } else if (bid < 96) {                      // attention output, 1 block/b
      const int b = bid - 32;
      unsigned long long tz0 = cload64((const unsigned long long*)(zpst + b * 4));
      unsigned long long tz1 = cload64((const unsigned long long*)(zpst + b * 4) + 1);
      float we = cload(wexpst + (size_t)b * 256 + tid);
      union { unsigned long long u; float f[2]; } z0, z1;
      z0.u = tz0; z1.u = tz1;
      float Z = z0.f[0] + z0.f[1] + z1.f[0] + z1.f[1];
      attn[(size_t)b * 65536 + (size_t)it * 256 + tid] = we * __builtin_amdgcn_rcpf(Z);
    }
    gbar(bar, gen);
  }

  // -------- final: log_softmax, wave-per-row (plain cached loads are safe:
  // logits lines were only ever sc1-written during the kernel, never cached) --
  for (int rit = 0; rit < 16; ++rit) {
    int row = bid * 64 + rit * 4 + w;
    float* xr = logits + (size_t)row * 512;
    f4v a = ((const f4v*)xr)[lane * 2];
    f4v b2 = ((const f4v*)xr)[lane * 2 + 1];
    float m = a[0];
#pragma unroll
    for (int j = 1; j < 4; ++j) m = fmaxf(m, a[j]);
#pragma unroll
    for (int j = 0; j < 4; ++j) m = fmaxf(m, b2[j]);
#pragma unroll
    for (int off = 32; off > 0; off >>= 1) m = fmaxf(m, __shfl_xor(m, off, 64));
    float sm = 0.f;
#pragma unroll
    for (int j = 0; j < 4; ++j) sm += __expf(a[j] - m) + __expf(b2[j] - m);
#pragma unroll
    for (int off = 32; off > 0; off >>= 1) sm += __shfl_xor(sm, off, 64);
    float lse = m + __logf(sm);
    f4v oa, ob;
#pragma unroll
    for (int j = 0; j < 4; ++j) { oa[j] = a[j] - lse; ob[j] = b2[j] - lse; }
    ((f4v*)xr)[lane * 2] = oa;
    ((f4v*)xr)[lane * 2 + 1] = ob;
  }
  {
    int i = bid * 256 + tid;                    // h_final (blocks 0..127)
    if (i < 32768) hfin[i] = cload(hst + i);
  }
}

// ---------------------------------------------------------------------------
extern "C" void kernel_launch(void* const* d_in, const int* in_sizes, int n_in,
                              void* d_out, int out_size, void* d_ws, size_t ws_size,
                              hipStream_t stream) {
  const float* enc  = (const float*)d_in[0];
  const float* Wa   = (const float*)d_in[1];
  const float* ba   = (const float*)d_in[2];
  const float* Ua   = (const float*)d_in[3];
  const float* bu   = (const float*)d_in[4];
  const float* Va   = (const float*)d_in[5];
  // d_in[6] = bv : constant shift, softmax-invariant -> unused
  const float* Wih  = (const float*)d_in[7];
  const float* bih  = (const float*)d_in[8];
  const float* Whh  = (const float*)d_in[9];
  const float* bhh  = (const float*)d_in[10];
  const float* Wout = (const float*)d_in[11];
  const float* bout = (const float*)d_in[12];
  (void)in_sizes; (void)n_in; (void)out_size;

  char* ws = (char*)d_ws;
  unsigned*       bar   = (unsigned*)(ws + OFF_BAR);
  float*          hst   = (float*)(ws + OFF_H);
  unsigned short* hbf   = (unsigned short*)(ws + OFF_HBF);
  float*          qst   = (float*)(ws + OFF_Q);
  float*          ghst  = (float*)(ws + OFF_GH);
  float*          ctxst = (float*)(ws + OFF_CTX);
  float*          zpst  = (float*)(ws + OFF_ZP);
  float*          wexp  = (float*)(ws + OFF_WEXP);
  unsigned short* wcat  = (unsigned short*)(ws + OFF_WCAT);
  unsigned short* wihb  = (unsigned short*)(ws + OFF_WIH);
  unsigned short* uab   = (unsigned short*)(ws + OFF_UAB);
  unsigned short* keysb = (unsigned short*)(ws + OFF_KEYS);
  unsigned char*  enc8  = (unsigned char*)(ws + OFF_ENC8);
  int use_enc8 = (ws_size >= (size_t)WS_FULL) ? 1 : 0;

  hipMemsetAsync(d_ws, 0, MEMSET_BYTES, stream);  // barrier + h + h_bf16 = 0
  prep_kernel<<<1024, 256, 0, stream>>>(Wa, Whh, Wout, Wih, Ua, enc,
                                        wcat, wihb, uab, enc8, use_enc8);
  keys_kernel<<<2048, 256, 0, stream>>>(enc, uab, bu, keysb);
  decoder_kernel<<<256, 256, 0, stream>>>(enc, ba, Va, bih, bhh, bout,
                                          wcat, wihb, keysb, enc8,
                                          bar, hst, hbf, qst, ghst, ctxst,
                                          zpst, wexp, (float*)d_out, use_enc8);
}